// Round 5
// baseline (208.084 us; speedup 1.0000x reference)
//
#include <hip/hip_runtime.h>

typedef unsigned short u16;
typedef unsigned int u32;
typedef __attribute__((ext_vector_type(8))) short s16x8;   // 8 bf16 (4 VGPR) MFMA A/B frag
typedef __attribute__((ext_vector_type(4))) float f32x4;   // MFMA C/D frag

// Problem dims: B=4, X=32, H=8, W=128, C=32 (all fp32 in/out)
// Attention view: 4096 keys, M=256 cols, 128 distinct query rows per batch.
//
// Pipeline: conv(->K,Vt) -> qproj -> scores(MFMA) -> softmax -> pv(MFMA) -> scatter
// Workspace aliasing (ws >= 25.8MB proven in round 2):
//  region A [0,8.4M):      S fp32 (scores->softmax) | Opart fp32 (pv->scatter)
//  region B [8.4M,16.8M):  K bf16 (conv->scores)    | P bf16 (softmax->pv)
//  region C [16.8M,25.2M): Vt bf16 (conv->pv)
//  region D [25.2M,+256K): Qbf bf16 (qproj->scores)
#define WS_A      0u
#define WS_B      8388608u
#define WS_C      16777216u
#define WS_D      25165824u
#define WS_NEEDED 25427968u

__device__ __forceinline__ u16 f2bf(float f){
  u32 u = __float_as_uint(f);
  return (u16)((u + 0x7fffu + ((u >> 16) & 1u)) >> 16);   // RNE
}

__global__ __launch_bounds__(256) void zero_out_kernel(float* __restrict__ out){
  int t = blockIdx.x * 256 + threadIdx.x;
  ((float4*)out)[t] = make_float4(0.f, 0.f, 0.f, 0.f);
}

// K1: Conv3d(32->64ch, k=(3,1,1), pad=(1,0,0)). One block = all 64 out channels
// for one (b, x, 32-wide w chunk). No LDS (round-4 had 8-way bank conflicts);
// results stored directly as scattered 2B stores — L2 merges full lines since
// the block covers all 256 m of each line set.
// K (o>=32) -> Kb[b][j][m]; V (o<32) -> Vt[b][m][j] (transpose fused here).
// j = ck*128 + x*4 + wc (block-uniform per o), m = wl*8 + h.
__global__ __launch_bounds__(256, 1) void conv_kernel(const float* __restrict__ storage,
    const float* __restrict__ w_cross, const float* __restrict__ b_cross,
    u16* __restrict__ Kb, u16* __restrict__ Vt){
  int bid = blockIdx.x;
  int wc = bid & 3;
  int x  = (bid >> 2) & 31;
  int b  = bid >> 7;
  int tid = threadIdx.x;
  int wl = tid & 31, h = tid >> 5;
  int w = wc * 32 + wl;

  float in[3][32];
  #pragma unroll
  for (int dx = 0; dx < 3; ++dx){
    int xx = x + dx - 1;
    if (xx < 0 || xx > 31){
      #pragma unroll
      for (int c = 0; c < 32; ++c) in[dx][c] = 0.f;
    } else {
      const float4* p = (const float4*)(storage + ((((size_t)b*32 + xx)*8 + h)*128 + w)*32);
      #pragma unroll
      for (int q = 0; q < 8; ++q){
        float4 v = p[q];
        in[dx][q*4+0] = v.x; in[dx][q*4+1] = v.y;
        in[dx][q*4+2] = v.z; in[dx][q*4+3] = v.w;
      }
    }
  }

  int m = wl*8 + h;
  size_t kbase = (size_t)b*1048576 + (size_t)x*1024 + (size_t)wc*256 + m;   // + ck*32768
  size_t vbase = ((size_t)b*256 + m)*4096 + (size_t)x*4 + wc;               // + ck*128

  #pragma unroll 1
  for (int og = 0; og < 8; ++og){
    u16 res[8];
    #pragma unroll
    for (int i = 0; i < 8; ++i){
      int o = og*8 + i;                       // block-uniform -> scalar weight loads
      const float* wp = w_cross + o * 96;     // [c*3 + dx]
      float acc = b_cross[o];
      #pragma unroll
      for (int c = 0; c < 32; ++c){
        acc += in[0][c]*wp[c*3+0] + in[1][c]*wp[c*3+1] + in[2][c]*wp[c*3+2];
      }
      res[i] = f2bf(acc);
    }
    if (og < 4){   // V channels: ck = og*8+i
      #pragma unroll
      for (int i = 0; i < 8; ++i) Vt[vbase + (size_t)(og*8 + i)*128] = res[i];
    } else {       // K channels: ck = og*8+i-32
      #pragma unroll
      for (int i = 0; i < 8; ++i) Kb[kbase + (size_t)(og*8 + i - 32)*32768] = res[i];
    }
  }
}

// K2: 1x1 q-projection -> Qbf bf16 [4][128][256] (row = cq*4+whi, col m).
__global__ __launch_bounds__(256) void qproj_kernel(const float* __restrict__ target,
    const float* __restrict__ w_q, const float* __restrict__ b_q, u16* __restrict__ Qbf){
  int bid = blockIdx.x;
  int wc = bid & 3;
  int cq = (bid >> 2) & 31;
  int b  = bid >> 7;
  int tid = threadIdx.x;
  int wl = tid & 31, h = tid >> 5;
  int w = wc * 32 + wl;
  float in[32];
  const float4* p = (const float4*)(target + (((size_t)b*8 + h)*128 + w)*32);
  #pragma unroll
  for (int q = 0; q < 8; ++q){
    float4 v = p[q];
    in[q*4+0] = v.x; in[q*4+1] = v.y; in[q*4+2] = v.z; in[q*4+3] = v.w;
  }
  float acc = b_q[cq];
  #pragma unroll
  for (int c = 0; c < 32; ++c) acc += in[c] * w_q[cq*32 + c];
  __shared__ float stg[256];
  stg[wl*8 + h] = acc;
  __syncthreads();
  Qbf[((size_t)b*128 + cq*4 + wc)*256 + tid] = f2bf(stg[tid]);
}

// K3: scores S = Q*K^T via mfma_f32_16x16x32_bf16.
// Block = (b, kc: 128-key chunk), all 128 rows. Grid 128. Whole chunk staged
// once in 64KB LDS (one barrier); XOR-swizzled 8-u16 blocks, conflict-free
// ds_read_b128. Q frags hoisted out of the key loop.
__global__ __launch_bounds__(256) void scores_kernel(const u16* __restrict__ Qbf,
    const u16* __restrict__ Kb, float* __restrict__ S){
  int kc = blockIdx.x & 31, b = blockIdx.x >> 5;
  int tid = threadIdx.x;
  int w = tid >> 6, lane = tid & 63, l15 = lane & 15, quad = lane >> 4;
  __shared__ u16 Ks[128 * 256];   // 64KB
  {
    int jl = tid >> 1, hf = tid & 1;   // 2 threads per key row, 16 uint4 each
    const uint4* src = (const uint4*)(Kb + ((size_t)(b*4096 + kc*128 + jl))*256 + hf*128);
    u16* drow = &Ks[jl*256];
    #pragma unroll
    for (int q = 0; q < 16; ++q){
      uint4 v = src[q];
      int B8 = hf*16 + q;
      *(uint4*)&drow[(B8 ^ (jl & 7))*8] = v;
    }
  }
  __syncthreads();

  #pragma unroll 1
  for (int rp = 0; rp < 4; ++rp){
    s16x8 a[2][8];
    #pragma unroll
    for (int rt = 0; rt < 2; ++rt){
      int row = (rp*2 + rt)*16 + l15;
      const u16* qp = Qbf + ((size_t)(b*128 + row))*256 + quad*8;
      #pragma unroll
      for (int ks = 0; ks < 8; ++ks) a[rt][ks] = *(const s16x8*)(qp + ks*32);
    }
    #pragma unroll
    for (int kt2 = 0; kt2 < 2; ++kt2){
      f32x4 c0 = {0.f,0.f,0.f,0.f}, c1 = {0.f,0.f,0.f,0.f};
      int krow = kt2*64 + w*16 + l15;
      #pragma unroll
      for (int ks = 0; ks < 8; ++ks){
        int B8 = ks*4 + quad;
        s16x8 bf = *(const s16x8*)&Ks[krow*256 + (B8 ^ (krow & 7))*8];
        c0 = __builtin_amdgcn_mfma_f32_16x16x32_bf16(a[0][ks], bf, c0, 0, 0, 0);
        c1 = __builtin_amdgcn_mfma_f32_16x16x32_bf16(a[1][ks], bf, c1, 0, 0, 0);
      }
      int keyg = kc*128 + kt2*64 + w*16 + l15;
      #pragma unroll
      for (int reg = 0; reg < 4; ++reg){
        int r0 = (rp*2 + 0)*16 + quad*4 + reg;
        int r1 = (rp*2 + 1)*16 + quad*4 + reg;
        S[((size_t)(b*128 + r0))*4096 + keyg] = c0[reg];
        S[((size_t)(b*128 + r1))*4096 + keyg] = c1[reg];
      }
    }
  }
}

// K4: full-row softmax over 4096 keys; writes normalized P bf16 [b][row][key].
__global__ __launch_bounds__(256) void softmax_kernel(const float* __restrict__ S,
    u16* __restrict__ P){
  int r = blockIdx.x & 127, b = blockIdx.x >> 7;
  const float* row = S + ((size_t)(b*128 + r))*4096;
  int tid = threadIdx.x;
  float v[16];
  const float4* p4 = (const float4*)(row + tid*16);
  #pragma unroll
  for (int q = 0; q < 4; ++q){
    float4 t = p4[q];
    v[q*4+0] = t.x; v[q*4+1] = t.y; v[q*4+2] = t.z; v[q*4+3] = t.w;
  }
  float mx = v[0];
  #pragma unroll
  for (int i = 1; i < 16; ++i) mx = fmaxf(mx, v[i]);
  #pragma unroll
  for (int off = 1; off < 64; off <<= 1) mx = fmaxf(mx, __shfl_xor(mx, off));
  __shared__ float sm[4], sl[4];
  int wid = tid >> 6;
  if ((tid & 63) == 0) sm[wid] = mx;
  __syncthreads();
  mx = fmaxf(fmaxf(sm[0], sm[1]), fmaxf(sm[2], sm[3]));
  float s = 0.f;
  #pragma unroll
  for (int i = 0; i < 16; ++i){ v[i] = __expf(v[i] - mx); s += v[i]; }
  #pragma unroll
  for (int off = 1; off < 64; off <<= 1) s += __shfl_xor(s, off);
  if ((tid & 63) == 0) sl[wid] = s;
  __syncthreads();
  float inv = 1.f / (sl[0] + sl[1] + sl[2] + sl[3]);
  u16 o[16];
  #pragma unroll
  for (int i = 0; i < 16; ++i) o[i] = f2bf(v[i] * inv);
  uint4 o0, o1;
  o0.x = (u32)o[0] | ((u32)o[1] << 16);  o0.y = (u32)o[2] | ((u32)o[3] << 16);
  o0.z = (u32)o[4] | ((u32)o[5] << 16);  o0.w = (u32)o[6] | ((u32)o[7] << 16);
  o1.x = (u32)o[8] | ((u32)o[9] << 16);  o1.y = (u32)o[10]| ((u32)o[11]<< 16);
  o1.z = (u32)o[12]| ((u32)o[13]<< 16);  o1.w = (u32)o[14]| ((u32)o[15]<< 16);
  uint4* dst = (uint4*)(P + ((size_t)(b*128 + r))*4096 + tid*16);
  dst[0] = o0; dst[1] = o1;
}

// K5: O = P*V computed as D = Vt_tile * P_tile (both operands key-contiguous).
// Block = (b, kq: 256-key split, mc: 64-col chunk), all 128 rows. Grid 256.
__global__ __launch_bounds__(256) void pv_kernel(const u16* __restrict__ P,
    const u16* __restrict__ Vt, float* __restrict__ Opart){
  int mc = blockIdx.x & 3, kq = (blockIdx.x >> 2) & 15, b = blockIdx.x >> 6;
  int tid = threadIdx.x;
  int w = tid >> 6, lane = tid & 63, l15 = lane & 15, quad = lane >> 4;
  __shared__ char smem[34816];
  u16* Ps  = (u16*)smem;             // [128][64] keys, XOR-swizzled 8-blocks
  u16* Vts = (u16*)(smem + 16384);   // [64][64]
  f32x4 c[8];
  #pragma unroll
  for (int nt = 0; nt < 8; ++nt) c[nt] = (f32x4){0.f,0.f,0.f,0.f};

  #pragma unroll 1
  for (int kt = 0; kt < 4; ++kt){
    {
      int prow = tid >> 1, half = tid & 1;
      const uint4* src = (const uint4*)(P + ((size_t)(b*128 + prow))*4096 + kq*256 + kt*64 + half*32);
      #pragma unroll
      for (int q = 0; q < 4; ++q){
        uint4 v = src[q];
        int B8 = half*4 + q;
        *(uint4*)&Ps[prow*64 + (B8 ^ (prow & 7))*8] = v;
      }
    }
    {
      int ml = tid >> 2, qg = tid & 3;
      const uint4* src = (const uint4*)(Vt + ((size_t)(b*256 + mc*64 + ml))*4096 + kq*256 + kt*64 + qg*16);
      #pragma unroll
      for (int s = 0; s < 2; ++s){
        uint4 v = src[s];
        int B8 = qg*2 + s;
        *(uint4*)&Vts[ml*64 + (B8 ^ (ml & 7))*8] = v;
      }
    }
    __syncthreads();
    int mlocal = w*16 + l15;
    #pragma unroll
    for (int ks2 = 0; ks2 < 2; ++ks2){
      int B8 = ks2*4 + quad;
      s16x8 af = *(const s16x8*)&Vts[mlocal*64 + (B8 ^ (mlocal & 7))*8];
      #pragma unroll
      for (int nt = 0; nt < 8; ++nt){
        int prow = nt*16 + l15;
        s16x8 bf = *(const s16x8*)&Ps[prow*64 + (B8 ^ (prow & 7))*8];
        c[nt] = __builtin_amdgcn_mfma_f32_16x16x32_bf16(af, bf, c[nt], 0, 0, 0);
      }
    }
    __syncthreads();
  }

  // epilogue: LDS transpose for coalesced partial stores
  float* Osh = (float*)smem;   // [128][68]
  #pragma unroll
  for (int nt = 0; nt < 8; ++nt){
    int prow = nt*16 + l15;
    *(f32x4*)&Osh[prow*68 + w*16 + quad*4] = c[nt];
  }
  __syncthreads();
  {
    int prow = tid >> 1, half = tid & 1;
    float* dst = Opart + ((size_t)((b*16 + kq)*128 + prow))*256 + mc*64 + half*32;
    const float* srow = &Osh[prow*68 + half*32];
    #pragma unroll
    for (int i = 0; i < 8; ++i) ((float4*)dst)[i] = ((const float4*)srow)[i];
  }
}

// K6: sum 16 k-split partials, broadcast-scatter to output (32 slots per row).
__global__ __launch_bounds__(256) void scatter_kernel(const float* __restrict__ Opart,
    float* __restrict__ out){
  int r = blockIdx.x & 127, b = blockIdx.x >> 7;
  int m = threadIdx.x;
  float o = 0.f;
  #pragma unroll
  for (int kq = 0; kq < 16; ++kq) o += Opart[((size_t)((b*16 + kq)*128 + r))*256 + m];
  int cq = r >> 2, whi = r & 3;
  size_t obase = ((size_t)b*32 + cq) * 32768;
  #pragma unroll
  for (int hh = 0; hh < 8; ++hh){
    #pragma unroll
    for (int wt = 0; wt < 4; ++wt){
      out[obase + hh*4096 + wt*1024 + whi*256 + m] = o;
    }
  }
}

extern "C" void kernel_launch(void* const* d_in, const int* in_sizes, int n_in,
                              void* d_out, int out_size, void* d_ws, size_t ws_size,
                              hipStream_t stream){
  const float* storage = (const float*)d_in[0];
  const float* target  = (const float*)d_in[1];
  const float* w_cross = (const float*)d_in[2];
  const float* b_cross = (const float*)d_in[3];
  const float* w_q     = (const float*)d_in[4];
  const float* b_q     = (const float*)d_in[5];
  float* out = (float*)d_out;

  if (ws_size < (size_t)WS_NEEDED){
    zero_out_kernel<<<dim3(4096), dim3(256), 0, stream>>>(out);
    return;
  }

  char* ws = (char*)d_ws;
  float* S     = (float*)(ws + WS_A);
  float* Opart = (float*)(ws + WS_A);   // aliases S (sequential consumers)
  u16*   Kb    = (u16*)(ws + WS_B);
  u16*   P     = (u16*)(ws + WS_B);     // aliases Kb
  u16*   Vt    = (u16*)(ws + WS_C);
  u16*   Qbf   = (u16*)(ws + WS_D);

  conv_kernel    <<<dim3(512), dim3(256), 0, stream>>>(storage, w_cross, b_cross, Kb, Vt);
  qproj_kernel   <<<dim3(512), dim3(256), 0, stream>>>(target, w_q, b_q, Qbf);
  scores_kernel  <<<dim3(128), dim3(256), 0, stream>>>(Qbf, Kb, S);
  softmax_kernel <<<dim3(512), dim3(256), 0, stream>>>(S, P);
  pv_kernel      <<<dim3(256), dim3(256), 0, stream>>>(P, Vt, Opart);
  scatter_kernel <<<dim3(512), dim3(256), 0, stream>>>(Opart, out);
}

// Round 6
// 170.840 us; speedup vs baseline: 1.2180x; 1.2180x over previous
//
#include <hip/hip_runtime.h>

typedef unsigned short u16;
typedef unsigned int u32;
typedef __attribute__((ext_vector_type(8))) short s16x8;   // 8 bf16 (4 VGPR) MFMA A/B frag
typedef __attribute__((ext_vector_type(4))) float f32x4;   // MFMA C/D frag

// Problem dims: B=4, X=32, H=8, W=128, C=32 (all fp32 in/out)
// Attention view: 4096 keys, M=256 cols, 128 distinct query rows per batch.
//
// Pipeline: transpose_w -> conv(->K,V [b][j][m]) -> qproj -> scores(MFMA)
//           -> softmax -> pv(MFMA, V transposed in-LDS) -> scatter
// Workspace aliasing (ws >= 25.8MB proven in round 2):
//  region A [0,8.4M):      S fp32 (scores->softmax) | Opart fp32 (pv->scatter)
//  region B [8.4M,16.8M):  K bf16 (conv->scores)    | P bf16 (softmax->pv)
//  region C [16.8M,25.2M): V bf16 (conv->pv), natural [b][j][m] layout
//  region D [25.2M,+128K): Qbf bf16 (qproj->scores)
//  region E [25.3M,+24K):  wT fp32 (transpose_w->conv)
#define WS_A      0u
#define WS_B      8388608u
#define WS_C      16777216u
#define WS_D      25165824u
#define WS_E      25296896u
#define WS_NEEDED 25427968u

__device__ __forceinline__ u16 f2bf(float f){
  u32 u = __float_as_uint(f);
  return (u16)((u + 0x7fffu + ((u >> 16) & 1u)) >> 16);   // RNE
}

__global__ __launch_bounds__(256) void zero_out_kernel(float* __restrict__ out){
  int t = blockIdx.x * 256 + threadIdx.x;
  ((float4*)out)[t] = make_float4(0.f, 0.f, 0.f, 0.f);
}

// K0: weight transpose wT[(c*3+dx)*64 + o] = w_cross[o*96 + c*3 + dx] so conv's
// o-inner loop reads 64 consecutive floats -> s_load_dwordx16 batches.
__global__ __launch_bounds__(256) void transpose_w(const float* __restrict__ w_cross,
    float* __restrict__ wT){
  int t = blockIdx.x * 256 + threadIdx.x;   // 6144 total
  wT[t] = w_cross[(t & 63) * 96 + (t >> 6)];
}

// K1: Conv3d(32->64ch, k=(3,1,1), pad=(1,0,0)). One block = all 64 out channels
// for one (b, x, 32-wide w chunk). acc[64] accumulators; per-dx input chunk is
// short-lived (no rematerializable long-lived array -> round-4/5's reload bug
// can't recur). Direct register->global u16 stores; the block covers every m of
// each 512B row, so L2 merges lines with zero amplification (round-4-proven).
// K (o>=32) and V (o<32) both land in [b][j][m]: j = ck*128 + x*4 + wc,
// m = wl*8 + h.
__global__ __launch_bounds__(256, 2) void conv_kernel(const float* __restrict__ storage,
    const float* __restrict__ wT, const float* __restrict__ b_cross,
    u16* __restrict__ Kb, u16* __restrict__ Vb){
  int bid = blockIdx.x;
  int wc = bid & 3;
  int x  = (bid >> 2) & 31;
  int b  = bid >> 7;
  int tid = threadIdx.x;
  int wl = tid & 31, h = tid >> 5;
  int w = wc * 32 + wl;

  float acc[64];
  #pragma unroll
  for (int o = 0; o < 64; ++o) acc[o] = b_cross[o];

  #pragma unroll
  for (int dx = 0; dx < 3; ++dx){
    int xx = x + dx - 1;
    if (xx < 0 || xx > 31) continue;   // block-uniform branch, skips 1/3 of work at edges
    float vv[32];
    const float4* p = (const float4*)(storage + ((((size_t)b*32 + xx)*8 + h)*128 + w)*32);
    #pragma unroll
    for (int q = 0; q < 8; ++q){
      float4 v = p[q];
      vv[q*4+0] = v.x; vv[q*4+1] = v.y; vv[q*4+2] = v.z; vv[q*4+3] = v.w;
    }
    #pragma unroll
    for (int c = 0; c < 32; ++c){
      float v = vv[c];
      const float* wp = wT + (c*3 + dx)*64;   // block-uniform -> scalar loads
      #pragma unroll
      for (int o = 0; o < 64; ++o) acc[o] = fmaf(v, wp[o], acc[o]);
    }
  }

  int m = wl*8 + h;
  size_t base = ((size_t)b*4096 + (size_t)x*4 + wc)*256 + m;   // + ck*128*256
  #pragma unroll
  for (int o = 0; o < 64; ++o){
    u16 r = f2bf(acc[o]);
    if (o < 32) Vb[base + (size_t)o*32768] = r;          // s_v = first 32 channels
    else        Kb[base + (size_t)(o - 32)*32768] = r;   // s_k = second 32
  }
}

// K2: 1x1 q-projection -> Qbf bf16 [4][128][256] (row = cq*4+whi, col m).
__global__ __launch_bounds__(256) void qproj_kernel(const float* __restrict__ target,
    const float* __restrict__ w_q, const float* __restrict__ b_q, u16* __restrict__ Qbf){
  int bid = blockIdx.x;
  int wc = bid & 3;
  int cq = (bid >> 2) & 31;
  int b  = bid >> 7;
  int tid = threadIdx.x;
  int wl = tid & 31, h = tid >> 5;
  int w = wc * 32 + wl;
  float in[32];
  const float4* p = (const float4*)(target + (((size_t)b*8 + h)*128 + w)*32);
  #pragma unroll
  for (int q = 0; q < 8; ++q){
    float4 v = p[q];
    in[q*4+0] = v.x; in[q*4+1] = v.y; in[q*4+2] = v.z; in[q*4+3] = v.w;
  }
  float acc = b_q[cq];
  #pragma unroll
  for (int c = 0; c < 32; ++c) acc += in[c] * w_q[cq*32 + c];
  __shared__ float stg[256];
  stg[wl*8 + h] = acc;
  __syncthreads();
  Qbf[((size_t)b*128 + cq*4 + wc)*256 + tid] = f2bf(stg[tid]);
}

// K3: scores S = Q*K^T via mfma_f32_16x16x32_bf16.
// Block = (b, kc: 128-key chunk), all 128 rows. Grid 128. Whole chunk staged
// once in 64KB LDS (one barrier); XOR-swizzled 8-u16 blocks, conflict-free
// ds_read_b128. Q frags hoisted out of the key loop.
__global__ __launch_bounds__(256) void scores_kernel(const u16* __restrict__ Qbf,
    const u16* __restrict__ Kb, float* __restrict__ S){
  int kc = blockIdx.x & 31, b = blockIdx.x >> 5;
  int tid = threadIdx.x;
  int w = tid >> 6, lane = tid & 63, l15 = lane & 15, quad = lane >> 4;
  __shared__ u16 Ks[128 * 256];   // 64KB
  {
    int jl = tid >> 1, hf = tid & 1;   // 2 threads per key row, 16 uint4 each
    const uint4* src = (const uint4*)(Kb + ((size_t)(b*4096 + kc*128 + jl))*256 + hf*128);
    u16* drow = &Ks[jl*256];
    #pragma unroll
    for (int q = 0; q < 16; ++q){
      uint4 v = src[q];
      int B8 = hf*16 + q;
      *(uint4*)&drow[(B8 ^ (jl & 7))*8] = v;
    }
  }
  __syncthreads();

  #pragma unroll 1
  for (int rp = 0; rp < 4; ++rp){
    s16x8 a[2][8];
    #pragma unroll
    for (int rt = 0; rt < 2; ++rt){
      int row = (rp*2 + rt)*16 + l15;
      const u16* qp = Qbf + ((size_t)(b*128 + row))*256 + quad*8;
      #pragma unroll
      for (int ks = 0; ks < 8; ++ks) a[rt][ks] = *(const s16x8*)(qp + ks*32);
    }
    #pragma unroll
    for (int kt2 = 0; kt2 < 2; ++kt2){
      f32x4 c0 = {0.f,0.f,0.f,0.f}, c1 = {0.f,0.f,0.f,0.f};
      int krow = kt2*64 + w*16 + l15;
      #pragma unroll
      for (int ks = 0; ks < 8; ++ks){
        int B8 = ks*4 + quad;
        s16x8 bf = *(const s16x8*)&Ks[krow*256 + (B8 ^ (krow & 7))*8];
        c0 = __builtin_amdgcn_mfma_f32_16x16x32_bf16(a[0][ks], bf, c0, 0, 0, 0);
        c1 = __builtin_amdgcn_mfma_f32_16x16x32_bf16(a[1][ks], bf, c1, 0, 0, 0);
      }
      int keyg = kc*128 + kt2*64 + w*16 + l15;
      #pragma unroll
      for (int reg = 0; reg < 4; ++reg){
        int r0 = (rp*2 + 0)*16 + quad*4 + reg;
        int r1 = (rp*2 + 1)*16 + quad*4 + reg;
        S[((size_t)(b*128 + r0))*4096 + keyg] = c0[reg];
        S[((size_t)(b*128 + r1))*4096 + keyg] = c1[reg];
      }
    }
  }
}

// K4: full-row softmax over 4096 keys; writes normalized P bf16 [b][row][key].
__global__ __launch_bounds__(256) void softmax_kernel(const float* __restrict__ S,
    u16* __restrict__ P){
  int r = blockIdx.x & 127, b = blockIdx.x >> 7;
  const float* row = S + ((size_t)(b*128 + r))*4096;
  int tid = threadIdx.x;
  float v[16];
  const float4* p4 = (const float4*)(row + tid*16);
  #pragma unroll
  for (int q = 0; q < 4; ++q){
    float4 t = p4[q];
    v[q*4+0] = t.x; v[q*4+1] = t.y; v[q*4+2] = t.z; v[q*4+3] = t.w;
  }
  float mx = v[0];
  #pragma unroll
  for (int i = 1; i < 16; ++i) mx = fmaxf(mx, v[i]);
  #pragma unroll
  for (int off = 1; off < 64; off <<= 1) mx = fmaxf(mx, __shfl_xor(mx, off));
  __shared__ float sm[4], sl[4];
  int wid = tid >> 6;
  if ((tid & 63) == 0) sm[wid] = mx;
  __syncthreads();
  mx = fmaxf(fmaxf(sm[0], sm[1]), fmaxf(sm[2], sm[3]));
  float s = 0.f;
  #pragma unroll
  for (int i = 0; i < 16; ++i){ v[i] = __expf(v[i] - mx); s += v[i]; }
  #pragma unroll
  for (int off = 1; off < 64; off <<= 1) s += __shfl_xor(s, off);
  if ((tid & 63) == 0) sl[wid] = s;
  __syncthreads();
  float inv = 1.f / (sl[0] + sl[1] + sl[2] + sl[3]);
  u16 o[16];
  #pragma unroll
  for (int i = 0; i < 16; ++i) o[i] = f2bf(v[i] * inv);
  uint4 o0, o1;
  o0.x = (u32)o[0] | ((u32)o[1] << 16);  o0.y = (u32)o[2] | ((u32)o[3] << 16);
  o0.z = (u32)o[4] | ((u32)o[5] << 16);  o0.w = (u32)o[6] | ((u32)o[7] << 16);
  o1.x = (u32)o[8] | ((u32)o[9] << 16);  o1.y = (u32)o[10]| ((u32)o[11]<< 16);
  o1.z = (u32)o[12]| ((u32)o[13]<< 16);  o1.w = (u32)o[14]| ((u32)o[15]<< 16);
  uint4* dst = (uint4*)(P + ((size_t)(b*128 + r))*4096 + tid*16);
  dst[0] = o0; dst[1] = o1;
}

// K5: O = P*V as D = V^T_tile * P_tile. V is transposed DURING LDS staging
// (reads natural [b][j][m] rows; ds_write_b16 to 64-consecutive-u16 runs =
// 2-way bank alias = free). Vts rows padded to 72 u16 to keep 16B alignment
// and conflict-free ds_read_b128. Block = (b, kq: 256-key, mc: 64-col). Grid 256.
__global__ __launch_bounds__(256) void pv_kernel(const u16* __restrict__ P,
    const u16* __restrict__ Vb, float* __restrict__ Opart){
  int mc = blockIdx.x & 3, kq = (blockIdx.x >> 2) & 15, b = blockIdx.x >> 6;
  int tid = threadIdx.x;
  int w = tid >> 6, lane = tid & 63, l15 = lane & 15, quad = lane >> 4;
  __shared__ alignas(16) char smem[34816];
  u16* Ps  = (u16*)smem;             // [128][64] keys, XOR-swizzled 8-blocks (16KB)
  u16* Vts = (u16*)(smem + 16384);   // [64 m][72 j] (9216B)
  f32x4 c[8];
  #pragma unroll
  for (int nt = 0; nt < 8; ++nt) c[nt] = (f32x4){0.f,0.f,0.f,0.f};

  int jl = tid & 63, mo = tid >> 6;

  #pragma unroll 1
  for (int kt = 0; kt < 4; ++kt){
    {
      int prow = tid >> 1, half = tid & 1;
      const uint4* src = (const uint4*)(P + ((size_t)(b*128 + prow))*4096 + kq*256 + kt*64 + half*32);
      #pragma unroll
      for (int q = 0; q < 4; ++q){
        uint4 v = src[q];
        int B8 = half*4 + q;
        *(uint4*)&Ps[prow*64 + (B8 ^ (prow & 7))*8] = v;
      }
    }
    {
      // V transpose-stage: thread reads 2 uint4 (8 m each) of key row jl,
      // scatters u16s to Vts[m][jl].
      const uint4* vsrc = (const uint4*)(Vb + ((size_t)(b*4096 + kq*256 + kt*64 + jl))*256 + mc*64);
      #pragma unroll
      for (int qq = 0; qq < 2; ++qq){
        int q8 = mo + qq*4;          // m-octet index 0..7
        uint4 v = vsrc[q8];
        u16* dst = &Vts[(q8*8)*72 + jl];
        dst[0*72] = (u16)(v.x & 0xffff); dst[1*72] = (u16)(v.x >> 16);
        dst[2*72] = (u16)(v.y & 0xffff); dst[3*72] = (u16)(v.y >> 16);
        dst[4*72] = (u16)(v.z & 0xffff); dst[5*72] = (u16)(v.z >> 16);
        dst[6*72] = (u16)(v.w & 0xffff); dst[7*72] = (u16)(v.w >> 16);
      }
    }
    __syncthreads();
    int mlocal = w*16 + l15;
    #pragma unroll
    for (int ks2 = 0; ks2 < 2; ++ks2){
      s16x8 af = *(const s16x8*)&Vts[mlocal*72 + ks2*32 + quad*8];
      int B8 = ks2*4 + quad;
      #pragma unroll
      for (int nt = 0; nt < 8; ++nt){
        int prow = nt*16 + l15;
        s16x8 bf = *(const s16x8*)&Ps[prow*64 + (B8 ^ (prow & 7))*8];
        c[nt] = __builtin_amdgcn_mfma_f32_16x16x32_bf16(af, bf, c[nt], 0, 0, 0);
      }
    }
    __syncthreads();
  }

  // epilogue: LDS transpose for coalesced partial stores
  float* Osh = (float*)smem;   // [128][68]
  #pragma unroll
  for (int nt = 0; nt < 8; ++nt){
    int prow = nt*16 + l15;
    *(f32x4*)&Osh[prow*68 + w*16 + quad*4] = c[nt];
  }
  __syncthreads();
  {
    int prow = tid >> 1, half = tid & 1;
    float* dst = Opart + ((size_t)((b*16 + kq)*128 + prow))*256 + mc*64 + half*32;
    const float* srow = &Osh[prow*68 + half*32];
    #pragma unroll
    for (int i = 0; i < 8; ++i) ((float4*)dst)[i] = ((const float4*)srow)[i];
  }
}

// K6: sum 16 k-split partials, broadcast-scatter to output (32 slots per row).
__global__ __launch_bounds__(256) void scatter_kernel(const float* __restrict__ Opart,
    float* __restrict__ out){
  int r = blockIdx.x & 127, b = blockIdx.x >> 7;
  int m = threadIdx.x;
  float o = 0.f;
  #pragma unroll
  for (int kq = 0; kq < 16; ++kq) o += Opart[((size_t)((b*16 + kq)*128 + r))*256 + m];
  int cq = r >> 2, whi = r & 3;
  size_t obase = ((size_t)b*32 + cq) * 32768;
  #pragma unroll
  for (int hh = 0; hh < 8; ++hh){
    #pragma unroll
    for (int wt = 0; wt < 4; ++wt){
      out[obase + hh*4096 + wt*1024 + whi*256 + m] = o;
    }
  }
}

extern "C" void kernel_launch(void* const* d_in, const int* in_sizes, int n_in,
                              void* d_out, int out_size, void* d_ws, size_t ws_size,
                              hipStream_t stream){
  const float* storage = (const float*)d_in[0];
  const float* target  = (const float*)d_in[1];
  const float* w_cross = (const float*)d_in[2];
  const float* b_cross = (const float*)d_in[3];
  const float* w_q     = (const float*)d_in[4];
  const float* b_q     = (const float*)d_in[5];
  float* out = (float*)d_out;

  if (ws_size < (size_t)WS_NEEDED){
    zero_out_kernel<<<dim3(4096), dim3(256), 0, stream>>>(out);
    return;
  }

  char* ws = (char*)d_ws;
  float* S     = (float*)(ws + WS_A);
  float* Opart = (float*)(ws + WS_A);   // aliases S (sequential consumers)
  u16*   Kb    = (u16*)(ws + WS_B);
  u16*   P     = (u16*)(ws + WS_B);     // aliases Kb
  u16*   Vb    = (u16*)(ws + WS_C);
  u16*   Qbf   = (u16*)(ws + WS_D);
  float* wT    = (float*)(ws + WS_E);

  transpose_w    <<<dim3(24),  dim3(256), 0, stream>>>(w_cross, wT);
  conv_kernel    <<<dim3(512), dim3(256), 0, stream>>>(storage, wT, b_cross, Kb, Vb);
  qproj_kernel   <<<dim3(512), dim3(256), 0, stream>>>(target, w_q, b_q, Qbf);
  scores_kernel  <<<dim3(128), dim3(256), 0, stream>>>(Qbf, Kb, S);
  softmax_kernel <<<dim3(512), dim3(256), 0, stream>>>(S, P);
  pv_kernel      <<<dim3(256), dim3(256), 0, stream>>>(P, Vb, Opart);
  scatter_kernel <<<dim3(512), dim3(256), 0, stream>>>(Opart, out);
}

// Round 7
// 144.889 us; speedup vs baseline: 1.4362x; 1.1791x over previous
//
#include <hip/hip_runtime.h>

typedef unsigned short u16;
typedef unsigned int u32;
typedef __attribute__((ext_vector_type(8))) short s16x8;   // 8 bf16 (4 VGPR) MFMA A/B frag
typedef __attribute__((ext_vector_type(4))) float f32x4;   // MFMA C/D frag

// Problem dims: B=4, X=32, H=8, W=128, C=32 (all fp32 in/out)
// Attention view: 4096 keys, M=256 cols, 128 distinct query rows per batch.
//
// Pipeline: transpose_w -> conv(->K,V [b][j][m]) -> qproj -> scores(MFMA)
//           -> softmax -> pv(MFMA, V transposed in-LDS) -> scatter
// Workspace aliasing (ws >= 25.8MB proven in round 2):
//  region A [0,8.4M):      S fp32 (scores->softmax) | Opart fp32 (pv->scatter)
//  region B [8.4M,16.8M):  K bf16 (conv->scores)    | P bf16 (softmax->pv)
//  region C [16.8M,25.2M): V bf16 (conv->pv), natural [b][j][m] layout
//  region D [25.2M,+128K): Qbf bf16 (qproj->scores)
//  region E [25.3M,+24K):  wT fp32 (transpose_w->conv)
#define WS_A      0u
#define WS_B      8388608u
#define WS_C      16777216u
#define WS_D      25165824u
#define WS_E      25296896u
#define WS_NEEDED 25427968u

__device__ __forceinline__ u16 f2bf(float f){
  u32 u = __float_as_uint(f);
  return (u16)((u + 0x7fffu + ((u >> 16) & 1u)) >> 16);   // RNE
}

__global__ __launch_bounds__(256) void zero_out_kernel(float* __restrict__ out){
  int t = blockIdx.x * 256 + threadIdx.x;
  ((float4*)out)[t] = make_float4(0.f, 0.f, 0.f, 0.f);
}

// K0: weight transpose wT[(c*3+dx)*64 + o] = w_cross[o*96 + c*3 + dx] so conv's
// o-inner loop reads 16 consecutive floats -> batched s_loads.
__global__ __launch_bounds__(256) void transpose_w(const float* __restrict__ w_cross,
    float* __restrict__ wT){
  int t = blockIdx.x * 256 + threadIdx.x;   // 6144 total
  wT[t] = w_cross[(t & 63) * 96 + (t >> 6)];
}

// K1: Conv3d(32->64ch, k=(3,1,1), pad=(1,0,0)).
// Round-6 post-mortem: acc[64]+96 inputs = 160-float working set -> compiler
// rematerialized input loads (VGPR=60, VALUBusy=17%). Fix: 16 channels per
// BLOCK (grid x4), so per-thread state = 16 acc + one 32-float dx chunk -> fits
// registers naturally; 4x more blocks hides L2 latency.
// Block = (b, x, wc, og2). Stores u16 direct to [b][j][m], j = ck*128+x*4+wc,
// m = wl*8+h; block covers all 256 m of each row -> zero write amplification
// (round-4/6-proven).
__global__ __launch_bounds__(256, 2) void conv_kernel(const float* __restrict__ storage,
    const float* __restrict__ wT, const float* __restrict__ b_cross,
    u16* __restrict__ Kb, u16* __restrict__ Vb){
  int bid = blockIdx.x;
  int wc  = bid & 3;
  int x   = (bid >> 2) & 31;
  int og2 = (bid >> 7) & 3;    // 16-channel group
  int b   = bid >> 9;
  int tid = threadIdx.x;
  int wl = tid & 31, h = tid >> 5;
  int w = wc * 32 + wl;
  int obase_ch = og2 * 16;

  float acc[16];
  #pragma unroll
  for (int i = 0; i < 16; ++i) acc[i] = b_cross[obase_ch + i];

  #pragma unroll
  for (int dx = 0; dx < 3; ++dx){
    int xx = x + dx - 1;
    if (xx < 0 || xx > 31) continue;   // block-uniform
    float vv[32];
    const float4* p = (const float4*)(storage + ((((size_t)b*32 + xx)*8 + h)*128 + w)*32);
    #pragma unroll
    for (int q = 0; q < 8; ++q){
      float4 v = p[q];
      vv[q*4+0] = v.x; vv[q*4+1] = v.y; vv[q*4+2] = v.z; vv[q*4+3] = v.w;
    }
    #pragma unroll
    for (int c = 0; c < 32; ++c){
      float v = vv[c];
      const float* wp = wT + (c*3 + dx)*64 + obase_ch;   // block-uniform scalars
      #pragma unroll
      for (int i = 0; i < 16; ++i) acc[i] = fmaf(v, wp[i], acc[i]);
    }
  }

  int m = wl*8 + h;
  size_t base = ((size_t)b*4096 + (size_t)x*4 + wc)*256 + m;   // + ck*128*256
  if (og2 < 2){   // V channels: ck = obase_ch + i
    #pragma unroll
    for (int i = 0; i < 16; ++i)
      Vb[base + (size_t)(obase_ch + i)*32768] = f2bf(acc[i]);
  } else {        // K channels: ck = obase_ch + i - 32
    #pragma unroll
    for (int i = 0; i < 16; ++i)
      Kb[base + (size_t)(obase_ch + i - 32)*32768] = f2bf(acc[i]);
  }
}

// K2: 1x1 q-projection -> Qbf bf16 [4][128][256] (row = cq*4+whi, col m).
__global__ __launch_bounds__(256) void qproj_kernel(const float* __restrict__ target,
    const float* __restrict__ w_q, const float* __restrict__ b_q, u16* __restrict__ Qbf){
  int bid = blockIdx.x;
  int wc = bid & 3;
  int cq = (bid >> 2) & 31;
  int b  = bid >> 7;
  int tid = threadIdx.x;
  int wl = tid & 31, h = tid >> 5;
  int w = wc * 32 + wl;
  float in[32];
  const float4* p = (const float4*)(target + (((size_t)b*8 + h)*128 + w)*32);
  #pragma unroll
  for (int q = 0; q < 8; ++q){
    float4 v = p[q];
    in[q*4+0] = v.x; in[q*4+1] = v.y; in[q*4+2] = v.z; in[q*4+3] = v.w;
  }
  float acc = b_q[cq];
  #pragma unroll
  for (int c = 0; c < 32; ++c) acc += in[c] * w_q[cq*32 + c];
  __shared__ float stg[256];
  stg[wl*8 + h] = acc;
  __syncthreads();
  Qbf[((size_t)b*128 + cq*4 + wc)*256 + tid] = f2bf(stg[tid]);
}

// K3: scores S = Q*K^T via mfma_f32_16x16x32_bf16.
// Block = (b, kc: 64-key chunk), all 128 rows. Grid 256. 32KB LDS -> up to
// 5 blocks/CU. XOR-swizzled 8-u16 blocks, conflict-free ds_read_b128.
__global__ __launch_bounds__(256) void scores_kernel(const u16* __restrict__ Qbf,
    const u16* __restrict__ Kb, float* __restrict__ S){
  int kc = blockIdx.x & 63, b = blockIdx.x >> 6;
  int tid = threadIdx.x;
  int w = tid >> 6, lane = tid & 63, l15 = lane & 15, quad = lane >> 4;
  __shared__ u16 Ks[64 * 256];   // 32KB
  {
    int jl = tid >> 2, hf = tid & 3;   // 4 threads per key row, 8 uint4 each
    const uint4* src = (const uint4*)(Kb + ((size_t)(b*4096 + kc*64 + jl))*256 + hf*64);
    u16* drow = &Ks[jl*256];
    #pragma unroll
    for (int q = 0; q < 8; ++q){
      uint4 v = src[q];
      int B8 = hf*8 + q;
      *(uint4*)&drow[(B8 ^ (jl & 7))*8] = v;
    }
  }
  __syncthreads();

  int krow = w*16 + l15;
  #pragma unroll 1
  for (int rp = 0; rp < 4; ++rp){
    s16x8 a[2][8];
    #pragma unroll
    for (int rt = 0; rt < 2; ++rt){
      int row = (rp*2 + rt)*16 + l15;
      const u16* qp = Qbf + ((size_t)(b*128 + row))*256 + quad*8;
      #pragma unroll
      for (int ks = 0; ks < 8; ++ks) a[rt][ks] = *(const s16x8*)(qp + ks*32);
    }
    f32x4 c0 = {0.f,0.f,0.f,0.f}, c1 = {0.f,0.f,0.f,0.f};
    #pragma unroll
    for (int ks = 0; ks < 8; ++ks){
      int B8 = ks*4 + quad;
      s16x8 bf = *(const s16x8*)&Ks[krow*256 + (B8 ^ (krow & 7))*8];
      c0 = __builtin_amdgcn_mfma_f32_16x16x32_bf16(a[0][ks], bf, c0, 0, 0, 0);
      c1 = __builtin_amdgcn_mfma_f32_16x16x32_bf16(a[1][ks], bf, c1, 0, 0, 0);
    }
    int keyg = kc*64 + krow;
    #pragma unroll
    for (int reg = 0; reg < 4; ++reg){
      int r0 = (rp*2 + 0)*16 + quad*4 + reg;
      int r1 = (rp*2 + 1)*16 + quad*4 + reg;
      S[((size_t)(b*128 + r0))*4096 + keyg] = c0[reg];
      S[((size_t)(b*128 + r1))*4096 + keyg] = c1[reg];
    }
  }
}

// K4: full-row softmax over 4096 keys; writes normalized P bf16 [b][row][key].
__global__ __launch_bounds__(256) void softmax_kernel(const float* __restrict__ S,
    u16* __restrict__ P){
  int r = blockIdx.x & 127, b = blockIdx.x >> 7;
  const float* row = S + ((size_t)(b*128 + r))*4096;
  int tid = threadIdx.x;
  float v[16];
  const float4* p4 = (const float4*)(row + tid*16);
  #pragma unroll
  for (int q = 0; q < 4; ++q){
    float4 t = p4[q];
    v[q*4+0] = t.x; v[q*4+1] = t.y; v[q*4+2] = t.z; v[q*4+3] = t.w;
  }
  float mx = v[0];
  #pragma unroll
  for (int i = 1; i < 16; ++i) mx = fmaxf(mx, v[i]);
  #pragma unroll
  for (int off = 1; off < 64; off <<= 1) mx = fmaxf(mx, __shfl_xor(mx, off));
  __shared__ float sm[4], sl[4];
  int wid = tid >> 6;
  if ((tid & 63) == 0) sm[wid] = mx;
  __syncthreads();
  mx = fmaxf(fmaxf(sm[0], sm[1]), fmaxf(sm[2], sm[3]));
  float s = 0.f;
  #pragma unroll
  for (int i = 0; i < 16; ++i){ v[i] = __expf(v[i] - mx); s += v[i]; }
  #pragma unroll
  for (int off = 1; off < 64; off <<= 1) s += __shfl_xor(s, off);
  if ((tid & 63) == 0) sl[wid] = s;
  __syncthreads();
  float inv = 1.f / (sl[0] + sl[1] + sl[2] + sl[3]);
  u16 o[16];
  #pragma unroll
  for (int i = 0; i < 16; ++i) o[i] = f2bf(v[i] * inv);
  uint4 o0, o1;
  o0.x = (u32)o[0] | ((u32)o[1] << 16);  o0.y = (u32)o[2] | ((u32)o[3] << 16);
  o0.z = (u32)o[4] | ((u32)o[5] << 16);  o0.w = (u32)o[6] | ((u32)o[7] << 16);
  o1.x = (u32)o[8] | ((u32)o[9] << 16);  o1.y = (u32)o[10]| ((u32)o[11]<< 16);
  o1.z = (u32)o[12]| ((u32)o[13]<< 16);  o1.w = (u32)o[14]| ((u32)o[15]<< 16);
  uint4* dst = (uint4*)(P + ((size_t)(b*128 + r))*4096 + tid*16);
  dst[0] = o0; dst[1] = o1;
}

// K5: O = P*V as D = V^T_tile * P_tile. V transposed DURING LDS staging
// (ds_write_b16 to 64-consecutive-u16 runs = 2-way alias = free). Vts rows
// padded to 72 u16 -> conflict-free ds_read_b128. Block = (b, kq, mc). Grid 256.
__global__ __launch_bounds__(256) void pv_kernel(const u16* __restrict__ P,
    const u16* __restrict__ Vb, float* __restrict__ Opart){
  int mc = blockIdx.x & 3, kq = (blockIdx.x >> 2) & 15, b = blockIdx.x >> 6;
  int tid = threadIdx.x;
  int w = tid >> 6, lane = tid & 63, l15 = lane & 15, quad = lane >> 4;
  __shared__ alignas(16) char smem[34816];
  u16* Ps  = (u16*)smem;             // [128][64] keys, XOR-swizzled 8-blocks (16KB)
  u16* Vts = (u16*)(smem + 16384);   // [64 m][72 j] (9216B)
  f32x4 c[8];
  #pragma unroll
  for (int nt = 0; nt < 8; ++nt) c[nt] = (f32x4){0.f,0.f,0.f,0.f};

  int jl = tid & 63, mo = tid >> 6;

  #pragma unroll 1
  for (int kt = 0; kt < 4; ++kt){
    {
      int prow = tid >> 1, half = tid & 1;
      const uint4* src = (const uint4*)(P + ((size_t)(b*128 + prow))*4096 + kq*256 + kt*64 + half*32);
      #pragma unroll
      for (int q = 0; q < 4; ++q){
        uint4 v = src[q];
        int B8 = half*4 + q;
        *(uint4*)&Ps[prow*64 + (B8 ^ (prow & 7))*8] = v;
      }
    }
    {
      const uint4* vsrc = (const uint4*)(Vb + ((size_t)(b*4096 + kq*256 + kt*64 + jl))*256 + mc*64);
      #pragma unroll
      for (int qq = 0; qq < 2; ++qq){
        int q8 = mo + qq*4;          // m-octet index 0..7
        uint4 v = vsrc[q8];
        u16* dst = &Vts[(q8*8)*72 + jl];
        dst[0*72] = (u16)(v.x & 0xffff); dst[1*72] = (u16)(v.x >> 16);
        dst[2*72] = (u16)(v.y & 0xffff); dst[3*72] = (u16)(v.y >> 16);
        dst[4*72] = (u16)(v.z & 0xffff); dst[5*72] = (u16)(v.z >> 16);
        dst[6*72] = (u16)(v.w & 0xffff); dst[7*72] = (u16)(v.w >> 16);
      }
    }
    __syncthreads();
    int mlocal = w*16 + l15;
    #pragma unroll
    for (int ks2 = 0; ks2 < 2; ++ks2){
      s16x8 af = *(const s16x8*)&Vts[mlocal*72 + ks2*32 + quad*8];
      int B8 = ks2*4 + quad;
      #pragma unroll
      for (int nt = 0; nt < 8; ++nt){
        int prow = nt*16 + l15;
        s16x8 bf = *(const s16x8*)&Ps[prow*64 + (B8 ^ (prow & 7))*8];
        c[nt] = __builtin_amdgcn_mfma_f32_16x16x32_bf16(af, bf, c[nt], 0, 0, 0);
      }
    }
    __syncthreads();
  }

  // epilogue: LDS transpose for coalesced partial stores
  float* Osh = (float*)smem;   // [128][68]
  #pragma unroll
  for (int nt = 0; nt < 8; ++nt){
    int prow = nt*16 + l15;
    *(f32x4*)&Osh[prow*68 + w*16 + quad*4] = c[nt];
  }
  __syncthreads();
  {
    int prow = tid >> 1, half = tid & 1;
    float* dst = Opart + ((size_t)((b*16 + kq)*128 + prow))*256 + mc*64 + half*32;
    const float* srow = &Osh[prow*68 + half*32];
    #pragma unroll
    for (int i = 0; i < 8; ++i) ((float4*)dst)[i] = ((const float4*)srow)[i];
  }
}

// K6: sum 16 k-split partials, broadcast-scatter to output (32 slots per row).
__global__ __launch_bounds__(256) void scatter_kernel(const float* __restrict__ Opart,
    float* __restrict__ out){
  int r = blockIdx.x & 127, b = blockIdx.x >> 7;
  int m = threadIdx.x;
  float o = 0.f;
  #pragma unroll
  for (int kq = 0; kq < 16; ++kq) o += Opart[((size_t)((b*16 + kq)*128 + r))*256 + m];
  int cq = r >> 2, whi = r & 3;
  size_t obase = ((size_t)b*32 + cq) * 32768;
  #pragma unroll
  for (int hh = 0; hh < 8; ++hh){
    #pragma unroll
    for (int wt = 0; wt < 4; ++wt){
      out[obase + hh*4096 + wt*1024 + whi*256 + m] = o;
    }
  }
}

extern "C" void kernel_launch(void* const* d_in, const int* in_sizes, int n_in,
                              void* d_out, int out_size, void* d_ws, size_t ws_size,
                              hipStream_t stream){
  const float* storage = (const float*)d_in[0];
  const float* target  = (const float*)d_in[1];
  const float* w_cross = (const float*)d_in[2];
  const float* b_cross = (const float*)d_in[3];
  const float* w_q     = (const float*)d_in[4];
  const float* b_q     = (const float*)d_in[5];
  float* out = (float*)d_out;

  if (ws_size < (size_t)WS_NEEDED){
    zero_out_kernel<<<dim3(4096), dim3(256), 0, stream>>>(out);
    return;
  }

  char* ws = (char*)d_ws;
  float* S     = (float*)(ws + WS_A);
  float* Opart = (float*)(ws + WS_A);   // aliases S (sequential consumers)
  u16*   Kb    = (u16*)(ws + WS_B);
  u16*   P     = (u16*)(ws + WS_B);     // aliases Kb
  u16*   Vb    = (u16*)(ws + WS_C);
  u16*   Qbf   = (u16*)(ws + WS_D);
  float* wT    = (float*)(ws + WS_E);

  transpose_w    <<<dim3(24),   dim3(256), 0, stream>>>(w_cross, wT);
  conv_kernel    <<<dim3(2048), dim3(256), 0, stream>>>(storage, wT, b_cross, Kb, Vb);
  qproj_kernel   <<<dim3(512),  dim3(256), 0, stream>>>(target, w_q, b_q, Qbf);
  scores_kernel  <<<dim3(256),  dim3(256), 0, stream>>>(Qbf, Kb, S);
  softmax_kernel <<<dim3(512),  dim3(256), 0, stream>>>(S, P);
  pv_kernel      <<<dim3(256),  dim3(256), 0, stream>>>(P, Vb, Opart);
  scatter_kernel <<<dim3(512),  dim3(256), 0, stream>>>(Opart, out);
}